// Round 2
// baseline (375.047 us; speedup 1.0000x reference)
//
#include <hip/hip_runtime.h>

// ---------------------------------------------------------------------------
// Attention_43087111914327: x[4,2048,512] -> qkv proj -> 7x11 local-window
// attention on 16x128 grid (8 heads, d=64) -> out proj. f32 in/out, bf16
// internal compute (threshold is 8*bf16_eps floor).
// ---------------------------------------------------------------------------

typedef __bf16 bf16x8 __attribute__((ext_vector_type(8)));
typedef float f32x4 __attribute__((ext_vector_type(4)));

__device__ __forceinline__ unsigned short f2bf(float f) {
  unsigned int u = __float_as_uint(f);
  u += 0x7FFFu + ((u >> 16) & 1u);   // round-to-nearest-even
  return (unsigned short)(u >> 16);
}
__device__ __forceinline__ float bf2f(unsigned short h) {
  return __uint_as_float(((unsigned int)h) << 16);
}

// ---------------------------------------------------------------------------
// f32 -> bf16 elementwise (vectorized float4 -> ushort4)
// ---------------------------------------------------------------------------
__global__ void cvt_f32_to_bf16_kernel(const float* __restrict__ in,
                                       unsigned short* __restrict__ out, int n4) {
  int i = blockIdx.x * blockDim.x + threadIdx.x;
  if (i >= n4) return;
  float4 v = reinterpret_cast<const float4*>(in)[i];
  ushort4 o;
  o.x = f2bf(v.x); o.y = f2bf(v.y); o.z = f2bf(v.z); o.w = f2bf(v.w);
  reinterpret_cast<ushort4*>(out)[i] = o;
}

// ---------------------------------------------------------------------------
// in[R][C] f32 -> out[C][R] bf16   (LDS 32x32 tile transpose)
// ---------------------------------------------------------------------------
__global__ void transpose_cvt_kernel(const float* __restrict__ in,
                                     unsigned short* __restrict__ out,
                                     int R, int C) {
  __shared__ float tile[32][33];
  int c0 = blockIdx.x * 32, r0 = blockIdx.y * 32;
  int tx = threadIdx.x, ty = threadIdx.y;  // block (32,8)
#pragma unroll
  for (int i = 0; i < 4; ++i)
    tile[ty + 8 * i][tx] = in[(size_t)(r0 + ty + 8 * i) * C + (c0 + tx)];
  __syncthreads();
#pragma unroll
  for (int i = 0; i < 4; ++i)
    out[(size_t)(c0 + ty + 8 * i) * R + (r0 + tx)] = f2bf(tile[tx][ty + 8 * i]);
}

// ---------------------------------------------------------------------------
// C[M,N] = A[M,K]_bf16 @ Bt[N,K]_bf16^T + bias[N]
// 128x128 tile, BK=64, 4 waves (2x2 of 64x64), mfma_f32_16x16x32_bf16,
// global_load_lds width-16 staging (m97 pattern).
// ---------------------------------------------------------------------------
template <bool OUT_BF16>
__global__ __launch_bounds__(256, 2)
void gemm_bt_kernel(const unsigned short* __restrict__ A,
                    const unsigned short* __restrict__ Bt,
                    const float* __restrict__ bias,
                    void* __restrict__ Cv, int M, int N, int K) {
  __shared__ unsigned short As[128 * 64];
  __shared__ unsigned short Bs[128 * 64];

  const int t = threadIdx.x;
  const int lane = t & 63, wv = t >> 6;
  const int wr = wv >> 1, wc = wv & 1;
  const int fr = lane & 15, fg = lane >> 4;
  const int m0 = blockIdx.x * 128, n0 = blockIdx.y * 128;

  f32x4 acc[4][4] = {};

  const int arow = t >> 3;          // 0..31
  const int acol = (t & 7) * 8;     // bf16 col, 16B per thread
  const unsigned short* Ag = A + (size_t)(m0 + arow) * K + acol;
  const unsigned short* Bg = Bt + (size_t)(n0 + arow) * K + acol;

  for (int k0 = 0; k0 < K; k0 += 64) {
    __syncthreads();  // previous tile's reads complete
#pragma unroll
    for (int it = 0; it < 4; ++it) {
      __builtin_amdgcn_global_load_lds(
          (const __attribute__((address_space(1))) unsigned int*)(Ag + (size_t)(it * 32) * K + k0),
          (__attribute__((address_space(3))) unsigned int*)(&As[(it * 32 + arow) * 64 + acol]),
          16, 0, 0);
    }
#pragma unroll
    for (int it = 0; it < 4; ++it) {
      __builtin_amdgcn_global_load_lds(
          (const __attribute__((address_space(1))) unsigned int*)(Bg + (size_t)(it * 32) * K + k0),
          (__attribute__((address_space(3))) unsigned int*)(&Bs[(it * 32 + arow) * 64 + acol]),
          16, 0, 0);
    }
    __syncthreads();  // compiler drains vmcnt before barrier

#pragma unroll
    for (int kk = 0; kk < 2; ++kk) {
      bf16x8 af[4], bfr[4];
#pragma unroll
      for (int m = 0; m < 4; ++m)
        af[m] = *(const bf16x8*)&As[(wr * 64 + m * 16 + fr) * 64 + kk * 32 + fg * 8];
#pragma unroll
      for (int n = 0; n < 4; ++n)
        bfr[n] = *(const bf16x8*)&Bs[(wc * 64 + n * 16 + fr) * 64 + kk * 32 + fg * 8];
#pragma unroll
      for (int m = 0; m < 4; ++m)
#pragma unroll
        for (int n = 0; n < 4; ++n)
          acc[m][n] = __builtin_amdgcn_mfma_f32_16x16x32_bf16(af[m], bfr[n], acc[m][n], 0, 0, 0);
    }
  }

  // epilogue: C/D layout col = lane&15, row = (lane>>4)*4 + r   [m89/m91]
#pragma unroll
  for (int m = 0; m < 4; ++m) {
#pragma unroll
    for (int n = 0; n < 4; ++n) {
#pragma unroll
      for (int r = 0; r < 4; ++r) {
        int row = m0 + wr * 64 + m * 16 + fg * 4 + r;
        int col = n0 + wc * 64 + n * 16 + fr;
        float v = acc[m][n][r] + bias[col];
        if (OUT_BF16)
          ((unsigned short*)Cv)[(size_t)row * N + col] = f2bf(v);
        else
          ((float*)Cv)[(size_t)row * N + col] = v;
      }
    }
  }
}

// ---------------------------------------------------------------------------
// Local-window attention. Grid: (4 w-chunks, 16 h-rows, 32 b*head).
// Block: 256 threads = 4 waves; each wave owns 8 queries.
// K staged transposed Kt[d][key] (stride 298 -> odd half-stride, conflict-free
// lanes-as-keys reads); V row-major Vs[key][d]; Q bf16.
// Phase A: lanes = key-slots (77 slots over 2 per lane), f32 dot over d.
// Softmax: wave shuffle reduce. Phase B: lanes = dims, p via __shfl broadcast.
// ---------------------------------------------------------------------------
#define KTS 298
#define NKMAX 294

__global__ __launch_bounds__(256, 2)
void attn_local_kernel(const unsigned short* __restrict__ qkv,
                       unsigned short* __restrict__ att) {
  __shared__ unsigned short Kt[64 * KTS];    // [d][key]
  __shared__ unsigned short Vs[NKMAX * 64];  // [key][d]
  __shared__ unsigned short Qs[32 * 64];     // [q][d]

  const int t = threadIdx.x, lane = t & 63, wv = t >> 6;
  const int w0 = blockIdx.x * 32;
  const int h = blockIdx.y;
  const int bh = blockIdx.z;
  const int b = bh >> 3, head = bh & 7;

  const int hlo = max(0, h - 3), hhi = min(15, h + 3);
  const int nh = hhi - hlo + 1;
  const int wlo = max(0, w0 - 5), whi = min(127, w0 + 36);
  const int nw = whi - wlo + 1;
  const int nkeys = nh * nw;

  const size_t base = (size_t)b * 2048 * 1536 + (size_t)head * 64;

  // ---- stage K (transposed), V ----
  {
    int kh = 0, kwi = wv;
    for (int idx = wv; idx < nkeys; idx += 4) {
      int n2 = (hlo + kh) * 128 + (wlo + kwi);
      const unsigned short* kp = qkv + base + (size_t)n2 * 1536 + 512;
      Kt[lane * KTS + idx] = kp[lane];        // K: col 512+head*64+d
      Vs[idx * 64 + lane] = kp[512 + lane];   // V: col 1024+head*64+d
      kwi += 4;
      if (kwi >= nw) { kwi -= nw; ++kh; }
    }
  }
  // ---- stage Q ----
  for (int q = wv; q < 32; q += 4) {
    int n = h * 128 + w0 + q;
    Qs[q * 64 + lane] = qkv[base + (size_t)n * 1536 + lane];
  }
  __syncthreads();

  // per-lane key-slot mapping: slot j -> (jh=j/11, jw=j%11)
  const int j2 = lane + 64;
  const int jh1 = lane / 11, jw1 = lane % 11;
  const int jh2 = j2 / 11, jw2 = j2 % 11;

  for (int qi = 0; qi < 8; ++qi) {
    const int q = wv * 8 + qi;
    const int w = w0 + q;
    const int kw1 = w - 5 + jw1, kw2 = w - 5 + jw2;
    const bool valid1 = (jh1 < nh) && (kw1 >= 0) && (kw1 <= 127);
    const bool valid2 = (jh2 < nh) && (kw2 >= 0) && (kw2 <= 127);
    const int ki1 = valid1 ? (jh1 * nw + (kw1 - wlo)) : 0;
    const int ki2 = valid2 ? (jh2 * nw + (kw2 - wlo)) : 0;

    float s1 = 0.f, s2 = 0.f;
#pragma unroll 8
    for (int d = 0; d < 64; ++d) {
      float qd = bf2f(Qs[q * 64 + d]);
      s1 += qd * bf2f(Kt[d * KTS + ki1]);
      s2 += qd * bf2f(Kt[d * KTS + ki2]);
    }
    s1 = valid1 ? s1 * 0.125f : -__builtin_inff();
    s2 = valid2 ? s2 * 0.125f : -__builtin_inff();

    float mx = fmaxf(s1, s2);
#pragma unroll
    for (int off = 32; off > 0; off >>= 1) mx = fmaxf(mx, __shfl_xor(mx, off));
    float p1 = valid1 ? __expf(s1 - mx) : 0.f;
    float p2 = valid2 ? __expf(s2 - mx) : 0.f;
    float sm = p1 + p2;
#pragma unroll
    for (int off = 32; off > 0; off >>= 1) sm += __shfl_xor(sm, off);
    const float rs = 1.0f / sm;

    // Phase B: lanes = dims; p[slot] broadcast from owning lane via shfl
    float o = 0.f;
    for (int jh = 0; jh < nh; ++jh) {
#pragma unroll
      for (int jw = 0; jw < 11; ++jw) {
        int kw = w - 5 + jw;
        if (kw < 0 || kw > 127) continue;      // uniform branch
        int ki = jh * nw + (kw - wlo);
        int slot = jh * 11 + jw;
        float p = (slot < 64) ? __shfl(p1, slot) : __shfl(p2, slot - 64);
        o += p * bf2f(Vs[ki * 64 + lane]);
      }
    }
    o *= rs;
    att[((size_t)b * 2048 + h * 128 + w) * 512 + head * 64 + lane] = f2bf(o);
  }
}

// ---------------------------------------------------------------------------
extern "C" void kernel_launch(void* const* d_in, const int* in_sizes, int n_in,
                              void* d_out, int out_size, void* d_ws, size_t ws_size,
                              hipStream_t stream) {
  const float* x      = (const float*)d_in[0];  // [4,2048,512]
  const float* w_qkv  = (const float*)d_in[1];  // [512,1536]
  const float* b_qkv  = (const float*)d_in[2];  // [1536]
  const float* w_proj = (const float*)d_in[3];  // [512,512]
  const float* b_proj = (const float*)d_in[4];  // [512]
  float* out = (float*)d_out;                   // [4,2048,512]

  char* ws = (char*)d_ws;
  unsigned short* xb     = (unsigned short*)(ws);             //  8,388,608 B (dead after GEMM1)
  unsigned short* att    = (unsigned short*)(ws);             //  aliases xb
  unsigned short* wqkvt  = (unsigned short*)(ws + 8388608);   //  1,572,864 B
  unsigned short* wprojt = (unsigned short*)(ws + 9961472);   //    524,288 B
  unsigned short* qkv    = (unsigned short*)(ws + 10485760);  // 25,165,824 B
  // total ws demand: 35,651,584 B

  // x -> bf16
  cvt_f32_to_bf16_kernel<<<4096, 256, 0, stream>>>(x, xb, 1048576);
  // w_qkv [512][1536] -> wqkvt [1536][512] bf16
  transpose_cvt_kernel<<<dim3(48, 16), dim3(32, 8), 0, stream>>>(w_qkv, wqkvt, 512, 1536);
  // w_proj [512][512] -> wprojt [512][512] bf16
  transpose_cvt_kernel<<<dim3(16, 16), dim3(32, 8), 0, stream>>>(w_proj, wprojt, 512, 512);

  // qkv = x @ w_qkv + b_qkv   (bf16 out)
  gemm_bt_kernel<true><<<dim3(64, 12), 256, 0, stream>>>(xb, wqkvt, b_qkv, qkv, 8192, 1536, 512);

  // local-window attention -> att (bf16, overwrites xb region)
  attn_local_kernel<<<dim3(4, 16, 32), 256, 0, stream>>>(qkv, att);

  // out = att @ w_proj + b_proj   (f32 out)
  gemm_bt_kernel<false><<<dim3(64, 4), 256, 0, stream>>>(att, wprojt, b_proj, out, 8192, 512, 512);
}

// Round 7
// 247.256 us; speedup vs baseline: 1.5168x; 1.5168x over previous
//
#include <hip/hip_runtime.h>

// ---------------------------------------------------------------------------
// Attention_43087111914327: x[4,2048,512] -> qkv proj -> 7x11 local-window
// attention on 16x128 grid (8 heads, d=64) -> out proj. f32 in/out, bf16
// internal compute (threshold is 8*bf16_eps floor).
// ---------------------------------------------------------------------------

typedef __bf16 bf16x8 __attribute__((ext_vector_type(8)));
typedef float f32x4 __attribute__((ext_vector_type(4)));

__device__ __forceinline__ unsigned short f2bf(float f) {
  unsigned int u = __float_as_uint(f);
  u += 0x7FFFu + ((u >> 16) & 1u);   // round-to-nearest-even
  return (unsigned short)(u >> 16);
}
__device__ __forceinline__ float bf2f(unsigned short h) {
  return __uint_as_float(((unsigned int)h) << 16);
}

// ---------------------------------------------------------------------------
// f32 -> bf16 elementwise (vectorized float4 -> ushort4)
// ---------------------------------------------------------------------------
__global__ void cvt_f32_to_bf16_kernel(const float* __restrict__ in,
                                       unsigned short* __restrict__ out, int n4) {
  int i = blockIdx.x * blockDim.x + threadIdx.x;
  if (i >= n4) return;
  float4 v = reinterpret_cast<const float4*>(in)[i];
  ushort4 o;
  o.x = f2bf(v.x); o.y = f2bf(v.y); o.z = f2bf(v.z); o.w = f2bf(v.w);
  reinterpret_cast<ushort4*>(out)[i] = o;
}

// ---------------------------------------------------------------------------
// in[R][C] f32 -> out[C][R] bf16   (LDS 32x32 tile transpose)
// ---------------------------------------------------------------------------
__global__ void transpose_cvt_kernel(const float* __restrict__ in,
                                     unsigned short* __restrict__ out,
                                     int R, int C) {
  __shared__ float tile[32][33];
  int c0 = blockIdx.x * 32, r0 = blockIdx.y * 32;
  int tx = threadIdx.x, ty = threadIdx.y;  // block (32,8)
#pragma unroll
  for (int i = 0; i < 4; ++i)
    tile[ty + 8 * i][tx] = in[(size_t)(r0 + ty + 8 * i) * C + (c0 + tx)];
  __syncthreads();
#pragma unroll
  for (int i = 0; i < 4; ++i)
    out[(size_t)(c0 + ty + 8 * i) * R + (r0 + tx)] = f2bf(tile[tx][ty + 8 * i]);
}

// ---------------------------------------------------------------------------
// C[M,N] = A[M,K]_bf16 @ Bt[N,K]_bf16^T + bias[N]
// 128x128 tile, BK=64, 4 waves (2x2 of 64x64), mfma_f32_16x16x32_bf16,
// global_load_lds width-16 staging (m97 pattern).
// ---------------------------------------------------------------------------
template <bool OUT_BF16>
__global__ __launch_bounds__(256, 2)
void gemm_bt_kernel(const unsigned short* __restrict__ A,
                    const unsigned short* __restrict__ Bt,
                    const float* __restrict__ bias,
                    void* __restrict__ Cv, int M, int N, int K) {
  __shared__ unsigned short As[128 * 64];
  __shared__ unsigned short Bs[128 * 64];

  const int t = threadIdx.x;
  const int lane = t & 63, wv = t >> 6;
  const int wr = wv >> 1, wc = wv & 1;
  const int fr = lane & 15, fg = lane >> 4;
  const int m0 = blockIdx.x * 128, n0 = blockIdx.y * 128;

  f32x4 acc[4][4] = {};

  const int arow = t >> 3;          // 0..31
  const int acol = (t & 7) * 8;     // bf16 col, 16B per thread
  const unsigned short* Ag = A + (size_t)(m0 + arow) * K + acol;
  const unsigned short* Bg = Bt + (size_t)(n0 + arow) * K + acol;

  for (int k0 = 0; k0 < K; k0 += 64) {
    __syncthreads();  // previous tile's reads complete
#pragma unroll
    for (int it = 0; it < 4; ++it) {
      __builtin_amdgcn_global_load_lds(
          (const __attribute__((address_space(1))) unsigned int*)(Ag + (size_t)(it * 32) * K + k0),
          (__attribute__((address_space(3))) unsigned int*)(&As[(it * 32 + arow) * 64 + acol]),
          16, 0, 0);
    }
#pragma unroll
    for (int it = 0; it < 4; ++it) {
      __builtin_amdgcn_global_load_lds(
          (const __attribute__((address_space(1))) unsigned int*)(Bg + (size_t)(it * 32) * K + k0),
          (__attribute__((address_space(3))) unsigned int*)(&Bs[(it * 32 + arow) * 64 + acol]),
          16, 0, 0);
    }
    __syncthreads();  // compiler drains vmcnt before barrier

#pragma unroll
    for (int kk = 0; kk < 2; ++kk) {
      bf16x8 af[4], bfr[4];
#pragma unroll
      for (int m = 0; m < 4; ++m)
        af[m] = *(const bf16x8*)&As[(wr * 64 + m * 16 + fr) * 64 + kk * 32 + fg * 8];
#pragma unroll
      for (int n = 0; n < 4; ++n)
        bfr[n] = *(const bf16x8*)&Bs[(wc * 64 + n * 16 + fr) * 64 + kk * 32 + fg * 8];
#pragma unroll
      for (int m = 0; m < 4; ++m)
#pragma unroll
        for (int n = 0; n < 4; ++n)
          acc[m][n] = __builtin_amdgcn_mfma_f32_16x16x32_bf16(af[m], bfr[n], acc[m][n], 0, 0, 0);
    }
  }

  // epilogue: C/D layout col = lane&15, row = (lane>>4)*4 + r   [m89/m91]
#pragma unroll
  for (int m = 0; m < 4; ++m) {
#pragma unroll
    for (int n = 0; n < 4; ++n) {
#pragma unroll
      for (int r = 0; r < 4; ++r) {
        int row = m0 + wr * 64 + m * 16 + fg * 4 + r;
        int col = n0 + wc * 64 + n * 16 + fr;
        float v = acc[m][n][r] + bias[col];
        if (OUT_BF16)
          ((unsigned short*)Cv)[(size_t)row * N + col] = f2bf(v);
        else
          ((float*)Cv)[(size_t)row * N + col] = v;
      }
    }
  }
}

// ---------------------------------------------------------------------------
// MFMA local-window attention.
// Grid: (8 w-chunks of 16, 16 h-rows, 32 b*head). Block: 256 = 4 waves.
// Block covers 16 queries (fixed h). Keys: nh (4..7) h-rows x 32 w-slots
// (kw = wlo + slot, clamped reads, masked by w-distance in-register; the
// staged h-rows are exactly the valid h-window, shared by all 16 queries).
//   Ks[slot][64]  bf16, elem-swizzle d ^ ((slot&7)<<3)   (QK B-operand)
//   Vt[d][256]    bf16, elem-swizzle s ^ (((d>>1)&7)<<3) (PV B-operand)
//   Pl[q][256]    bf16, elem-swizzle s ^ ((q&7)<<3)      (PV A-operand)
// Waves split the 2*nh S-tiles (strided); softmax stats via 16-lane shfl
// reduce + tiny LDS cross-wave combine; normalization deferred to epilogue.
// ---------------------------------------------------------------------------
#define VTS 256
#define PLS 256

__global__ __launch_bounds__(256, 2)
void attn_local_kernel(const unsigned short* __restrict__ qkv,
                       unsigned short* __restrict__ att) {
  __shared__ unsigned short Ks[224 * 64];
  __shared__ unsigned short Vt[64 * VTS];
  __shared__ unsigned short Pl[16 * PLS];
  __shared__ float red[2][4][16];

  const int t = threadIdx.x, lane = t & 63, wv = t >> 6;
  const int col = lane & 15, fg = lane >> 4;
  const int w0 = blockIdx.x * 16;
  const int h = blockIdx.y;
  const int bh = blockIdx.z;
  const int b = bh >> 3, head = bh & 7;

  const int hlo = max(0, h - 3), hhi = min(15, h + 3);
  const int nh = hhi - hlo + 1;          // 4..7
  const int wlo = max(0, w0 - 5);
  const int ntiles = 2 * nh;             // 16-key S tiles
  const int nslots = nh * 32;

  const size_t base = (size_t)b * 2048 * 1536 + (size_t)head * 64;

  // ---- Q fragments (A-operand): row = lane&15 (q), k = fg*8 + j ----
  bf16x8 qf[2];
  {
    const unsigned short* qp = qkv + base + (size_t)(h * 128 + w0 + col) * 1536 + fg * 8;
    qf[0] = *(const bf16x8*)(qp);
    qf[1] = *(const bf16x8*)(qp + 32);
  }

  // ---- stage K (swizzled row-major) and V (swizzled d-major) ----
  {
    const int half = lane >> 5;          // 0 -> K row, 1 -> V row
    const int e0 = (lane & 31) * 2;      // element pair within the 64-d row
    const int vz = ((e0 >> 1) & 7) << 3;
    for (int s = wv; s < nslots; s += 4) {
      int sh = s >> 5, sw = s & 31;
      int kw = min(wlo + sw, 127);       // clamp (over-staged slots are masked)
      const unsigned short* kp =
          qkv + base + (size_t)((hlo + sh) * 128 + kw) * 1536 + 512 + half * 512 + e0;
      unsigned int d32 = *(const unsigned int*)kp;
      if (half == 0) {
        *(unsigned int*)&Ks[s * 64 + (e0 ^ ((s & 7) << 3))] = d32;
      } else {
        Vt[e0 * VTS + (s ^ vz)]       = (unsigned short)(d32 & 0xffffu);
        Vt[(e0 + 1) * VTS + (s ^ vz)] = (unsigned short)(d32 >> 16);
      }
    }
  }
  __syncthreads();

  // ---- QK^T: wave handles tiles wv, wv+4, wv+8, wv+12 (if < ntiles) ----
  f32x4 acc[4];
#pragma unroll
  for (int i = 0; i < 4; ++i) acc[i] = (f32x4){0.f, 0.f, 0.f, 0.f};
#pragma unroll
  for (int i = 0; i < 4; ++i) {
    const int tile = wv + i * 4;
    if (tile < ntiles) {
      const int srow = tile * 16 + col;
      const unsigned short* kb = &Ks[srow * 64];
      const int sz = (srow & 7) << 3;
      bf16x8 k0 = *(const bf16x8*)&kb[(fg * 8) ^ sz];
      bf16x8 k1 = *(const bf16x8*)&kb[(32 + fg * 8) ^ sz];
      acc[i] = __builtin_amdgcn_mfma_f32_16x16x32_bf16(qf[0], k0, acc[i], 0, 0, 0);
      acc[i] = __builtin_amdgcn_mfma_f32_16x16x32_bf16(qf[1], k1, acc[i], 0, 0, 0);
    }
  }

  // ---- scale + w-distance mask (S layout: col=lane&15=key, row=fg*4+r=q) ----
#pragma unroll
  for (int i = 0; i < 4; ++i) {
    const int tile = wv + i * 4;
    if (tile < ntiles) {
      const int kw = wlo + (tile & 1) * 16 + col;
#pragma unroll
      for (int r = 0; r < 4; ++r) {
        const int dw = kw - (w0 + fg * 4 + r);
        const bool valid = (dw >= -5) && (dw <= 5) && (kw <= 127);
        acc[i][r] = valid ? acc[i][r] * 0.125f : -__builtin_inff();
      }
    }
  }

  // ---- row max: reduce over own tiles, then 16-lane shuffle, then LDS ----
  float gm[4], gs[4];
#pragma unroll
  for (int r = 0; r < 4; ++r) {
    float m = acc[0][r];
#pragma unroll
    for (int i = 1; i < 4; ++i)
      if (wv + i * 4 < ntiles) m = fmaxf(m, acc[i][r]);
#pragma unroll
    for (int off = 1; off <= 8; off <<= 1) m = fmaxf(m, __shfl_xor(m, off));
    if (col == 0) red[0][wv][fg * 4 + r] = m;
  }
  __syncthreads();
#pragma unroll
  for (int r = 0; r < 4; ++r) {
    const int row = fg * 4 + r;
    gm[r] = fmaxf(fmaxf(red[0][0][row], red[0][1][row]),
                  fmaxf(red[0][2][row], red[0][3][row]));
  }

  // ---- p = exp(s - max), row sums, write P (bf16, swizzled) ----
  float s4[4] = {0.f, 0.f, 0.f, 0.f};
#pragma unroll
  for (int i = 0; i < 4; ++i) {
    const int tile = wv + i * 4;
    if (tile < ntiles) {
#pragma unroll
      for (int r = 0; r < 4; ++r) {
        const float p = __expf(acc[i][r] - gm[r]);   // -inf -> 0
        s4[r] += p;
        const int row = fg * 4 + r;
        Pl[row * PLS + ((tile * 16 + col) ^ ((row & 7) << 3))] = f2bf(p);
      }
    }
  }
#pragma unroll
  for (int r = 0; r < 4; ++r) {
    float ss = s4[r];
#pragma unroll
    for (int off = 1; off <= 8; off <<= 1) ss += __shfl_xor(ss, off);
    if (col == 0) red[1][wv][fg * 4 + r] = ss;
  }
  __syncthreads();   // covers Pl writes + red[1]
#pragma unroll
  for (int r = 0; r < 4; ++r) {
    const int row = fg * 4 + r;
    gs[r] = (red[1][0][row] + red[1][1][row]) + (red[1][2][row] + red[1][3][row]);
  }

  // ---- PV: O[16q x 16d per wave]; A = Pl rows, B = Vt rows (d-major) ----
  f32x4 o = (f32x4){0.f, 0.f, 0.f, 0.f};
  const int dcol = wv * 16 + col;                       // this wave's d
  const unsigned short* vb = &Vt[dcol * VTS];
  const int vz = ((dcol >> 1) & 7) << 3;
  const int pz = (col & 7) << 3;                        // A row = col (=q)
  for (int ks = 0; ks < nh; ++ks) {
    const int kb = ks * 32 + fg * 8;
    bf16x8 pa = *(const bf16x8*)&Pl[col * PLS + (kb ^ pz)];
    bf16x8 vf = *(const bf16x8*)&vb[kb ^ vz];
    o = __builtin_amdgcn_mfma_f32_16x16x32_bf16(pa, vf, o, 0, 0, 0);
  }

  // ---- normalize + store ----
#pragma unroll
  for (int r = 0; r < 4; ++r) {
    const int row = fg * 4 + r;
    const float val = o[r] / gs[r];
    att[((size_t)b * 2048 + h * 128 + w0 + row) * 512 + head * 64 + dcol] = f2bf(val);
  }
}

// ---------------------------------------------------------------------------
extern "C" void kernel_launch(void* const* d_in, const int* in_sizes, int n_in,
                              void* d_out, int out_size, void* d_ws, size_t ws_size,
                              hipStream_t stream) {
  const float* x      = (const float*)d_in[0];  // [4,2048,512]
  const float* w_qkv  = (const float*)d_in[1];  // [512,1536]
  const float* b_qkv  = (const float*)d_in[2];  // [1536]
  const float* w_proj = (const float*)d_in[3];  // [512,512]
  const float* b_proj = (const float*)d_in[4];  // [512]
  float* out = (float*)d_out;                   // [4,2048,512]

  char* ws = (char*)d_ws;
  unsigned short* xb     = (unsigned short*)(ws);             //  8,388,608 B (dead after GEMM1)
  unsigned short* att    = (unsigned short*)(ws);             //  aliases xb
  unsigned short* wqkvt  = (unsigned short*)(ws + 8388608);   //  1,572,864 B
  unsigned short* wprojt = (unsigned short*)(ws + 9961472);   //    524,288 B
  unsigned short* qkv    = (unsigned short*)(ws + 10485760);  // 25,165,824 B
  // total ws demand: 35,651,584 B

  // x -> bf16
  cvt_f32_to_bf16_kernel<<<4096, 256, 0, stream>>>(x, xb, 1048576);
  // w_qkv [512][1536] -> wqkvt [1536][512] bf16
  transpose_cvt_kernel<<<dim3(48, 16), dim3(32, 8), 0, stream>>>(w_qkv, wqkvt, 512, 1536);
  // w_proj [512][512] -> wprojt [512][512] bf16
  transpose_cvt_kernel<<<dim3(16, 16), dim3(32, 8), 0, stream>>>(w_proj, wprojt, 512, 512);

  // qkv = x @ w_qkv + b_qkv   (bf16 out)
  gemm_bt_kernel<true><<<dim3(64, 12), 256, 0, stream>>>(xb, wqkvt, b_qkv, qkv, 8192, 1536, 512);

  // local-window attention -> att (bf16, overwrites xb region)
  attn_local_kernel<<<dim3(8, 16, 32), 256, 0, stream>>>(qkv, att);

  // out = att @ w_proj + b_proj   (f32 out)
  gemm_bt_kernel<false><<<dim3(64, 4), 256, 0, stream>>>(att, wprojt, b_proj, out, 8192, 512, 512);
}

// Round 12
// 146.130 us; speedup vs baseline: 2.5665x; 1.6920x over previous
//
#include <hip/hip_runtime.h>

// ---------------------------------------------------------------------------
// Attention_43087111914327: x[4,2048,512] -> qkv proj -> 7x11 local-window
// attention on 16x128 grid (8 heads, d=64) -> out proj. f32 in/out, bf16
// internal compute (threshold is 8*bf16_eps floor).
// ---------------------------------------------------------------------------

typedef __bf16 bf16x8 __attribute__((ext_vector_type(8)));
typedef float f32x4 __attribute__((ext_vector_type(4)));

__device__ __forceinline__ unsigned short f2bf(float f) {
  unsigned int u = __float_as_uint(f);
  u += 0x7FFFu + ((u >> 16) & 1u);   // round-to-nearest-even
  return (unsigned short)(u >> 16);
}
__device__ __forceinline__ float bf2f(unsigned short h) {
  return __uint_as_float(((unsigned int)h) << 16);
}

// ---------------------------------------------------------------------------
// f32 -> bf16 elementwise (vectorized float4 -> ushort4)
// ---------------------------------------------------------------------------
__global__ void cvt_f32_to_bf16_kernel(const float* __restrict__ in,
                                       unsigned short* __restrict__ out, int n4) {
  int i = blockIdx.x * blockDim.x + threadIdx.x;
  if (i >= n4) return;
  float4 v = reinterpret_cast<const float4*>(in)[i];
  ushort4 o;
  o.x = f2bf(v.x); o.y = f2bf(v.y); o.z = f2bf(v.z); o.w = f2bf(v.w);
  reinterpret_cast<ushort4*>(out)[i] = o;
}

// ---------------------------------------------------------------------------
// in[R][C] f32 -> out[C][R] bf16   (LDS 32x32 tile transpose)
// ---------------------------------------------------------------------------
__global__ void transpose_cvt_kernel(const float* __restrict__ in,
                                     unsigned short* __restrict__ out,
                                     int R, int C) {
  __shared__ float tile[32][33];
  int c0 = blockIdx.x * 32, r0 = blockIdx.y * 32;
  int tx = threadIdx.x, ty = threadIdx.y;  // block (32,8)
#pragma unroll
  for (int i = 0; i < 4; ++i)
    tile[ty + 8 * i][tx] = in[(size_t)(r0 + ty + 8 * i) * C + (c0 + tx)];
  __syncthreads();
#pragma unroll
  for (int i = 0; i < 4; ++i)
    out[(size_t)(c0 + ty + 8 * i) * R + (r0 + tx)] = f2bf(tile[tx][ty + 8 * i]);
}

// ---------------------------------------------------------------------------
// C[M,N] = A[M,K]_bf16 @ Bt[N,K]_bf16^T + bias[N]
// 128x128 tile, BK=64, 4 waves (2x2 of 64x64), mfma_f32_16x16x32_bf16,
// global_load_lds width-16 staging (m97 pattern).
// ---------------------------------------------------------------------------
template <bool OUT_BF16>
__global__ __launch_bounds__(256, 2)
void gemm_bt_kernel(const unsigned short* __restrict__ A,
                    const unsigned short* __restrict__ Bt,
                    const float* __restrict__ bias,
                    void* __restrict__ Cv, int M, int N, int K) {
  __shared__ unsigned short As[128 * 64];
  __shared__ unsigned short Bs[128 * 64];

  const int t = threadIdx.x;
  const int lane = t & 63, wv = t >> 6;
  const int wr = wv >> 1, wc = wv & 1;
  const int fr = lane & 15, fg = lane >> 4;
  const int m0 = blockIdx.x * 128, n0 = blockIdx.y * 128;

  f32x4 acc[4][4] = {};

  const int arow = t >> 3;          // 0..31
  const int acol = (t & 7) * 8;     // bf16 col, 16B per thread
  const unsigned short* Ag = A + (size_t)(m0 + arow) * K + acol;
  const unsigned short* Bg = Bt + (size_t)(n0 + arow) * K + acol;

  for (int k0 = 0; k0 < K; k0 += 64) {
    __syncthreads();  // previous tile's reads complete
#pragma unroll
    for (int it = 0; it < 4; ++it) {
      __builtin_amdgcn_global_load_lds(
          (const __attribute__((address_space(1))) unsigned int*)(Ag + (size_t)(it * 32) * K + k0),
          (__attribute__((address_space(3))) unsigned int*)(&As[(it * 32 + arow) * 64 + acol]),
          16, 0, 0);
    }
#pragma unroll
    for (int it = 0; it < 4; ++it) {
      __builtin_amdgcn_global_load_lds(
          (const __attribute__((address_space(1))) unsigned int*)(Bg + (size_t)(it * 32) * K + k0),
          (__attribute__((address_space(3))) unsigned int*)(&Bs[(it * 32 + arow) * 64 + acol]),
          16, 0, 0);
    }
    __syncthreads();  // compiler drains vmcnt before barrier

#pragma unroll
    for (int kk = 0; kk < 2; ++kk) {
      bf16x8 af[4], bfr[4];
#pragma unroll
      for (int m = 0; m < 4; ++m)
        af[m] = *(const bf16x8*)&As[(wr * 64 + m * 16 + fr) * 64 + kk * 32 + fg * 8];
#pragma unroll
      for (int n = 0; n < 4; ++n)
        bfr[n] = *(const bf16x8*)&Bs[(wc * 64 + n * 16 + fr) * 64 + kk * 32 + fg * 8];
#pragma unroll
      for (int m = 0; m < 4; ++m)
#pragma unroll
        for (int n = 0; n < 4; ++n)
          acc[m][n] = __builtin_amdgcn_mfma_f32_16x16x32_bf16(af[m], bfr[n], acc[m][n], 0, 0, 0);
    }
  }

  // epilogue: C/D layout col = lane&15, row = (lane>>4)*4 + r   [m89/m91]
#pragma unroll
  for (int m = 0; m < 4; ++m) {
#pragma unroll
    for (int n = 0; n < 4; ++n) {
#pragma unroll
      for (int r = 0; r < 4; ++r) {
        int row = m0 + wr * 64 + m * 16 + fg * 4 + r;
        int col = n0 + wc * 64 + n * 16 + fr;
        float v = acc[m][n][r] + bias[col];
        if (OUT_BF16)
          ((unsigned short*)Cv)[(size_t)row * N + col] = f2bf(v);
        else
          ((float*)Cv)[(size_t)row * N + col] = v;
      }
    }
  }
}

// ---------------------------------------------------------------------------
// MFMA local-window attention, v3c (gather-K, packed-V staging).
// Grid: (8 w-chunks of 16, 16 h-rows, 32 b*head). Block: 256 = 4 waves.
// - Q and K fragments: DIRECT global b128 gathers (no LDS, no barrier).
// - V: x4 global loads (8 rows/wave/iter), shfl-pair pack to dwords,
//   chunk-XOR-swizzled Vt2[d][pair], row stride 120 dwords (480B, 16B-aligned).
//   Chunk swizzle cz = c ^ (u&3): XOR on bits 0..1 ONLY — closed over the
//   chunk range 0..27 (max idx cz*4+pc = 111 < 120). Bit-2 XOR (v3b) escaped
//   to cz=31 -> idx 127 -> row overflow = round-10/11 latent bug.
//   Write ~2-way (u vs u+4, free); PV read = uniform over 4-bank spans.
// - Pl[q][slot] stride 256 (q-swizzle spans full 0..255; 232 overflowed).
// LDS = 30720 (Vt2) + 8192 (Pl) + 512 (red) = 39424 B -> 4 blocks/CU.
// ---------------------------------------------------------------------------
#define PLS 256
#define VTS2 120

__global__ __launch_bounds__(256, 4)
void attn_local_kernel(const unsigned short* __restrict__ qkv,
                       unsigned short* __restrict__ att) {
  __shared__ unsigned int Vt2[64 * VTS2];      // 30720 B
  __shared__ unsigned short Pl[16 * PLS];      //  8192 B
  __shared__ float red[2][4][16];              //   512 B

  const int t = threadIdx.x, lane = t & 63, wv = t >> 6;
  const int col = lane & 15, fg = lane >> 4;
  const int w0 = blockIdx.x * 16;
  const int h = blockIdx.y;
  const int bh = blockIdx.z;
  const int b = bh >> 3, head = bh & 7;

  const int hlo = max(0, h - 3), hhi = min(15, h + 3);
  const int nh = hhi - hlo + 1;          // 4..7
  const int wlo = max(0, w0 - 5);
  const int ntiles = 2 * nh;             // 16-key S tiles (>= 8)

  const size_t base = (size_t)b * 2048 * 1536 + (size_t)head * 64;

  // ---- V gathers: row r = wv*56 + i*8 + (lane>>3), 16B at d0=(lane&7)*8 ----
  const int u = lane & 7, v = lane >> 3;
  int4 mv[7];
#pragma unroll
  for (int i = 0; i < 7; ++i) {
    const int r = wv * 56 + i * 8 + v;
    const int hh = min(hlo + (r >> 5), 15);
    const int kw = min(wlo + (r & 31), 127);
    mv[i] = *(const int4*)(qkv + base + (size_t)(hh * 128 + kw) * 1536 + 1024 + u * 8);
  }

  // ---- Q fragments (A-operand): row = lane&15 (q), k = fg*8 + j ----
  bf16x8 qf[2];
  {
    const unsigned short* qp = qkv + base + (size_t)(h * 128 + w0 + col) * 1536 + fg * 8;
    qf[0] = *(const bf16x8*)(qp);
    qf[1] = *(const bf16x8*)(qp + 32);
  }

  // ---- K fragments (B-operand), direct gather: slot = tile*16+col ----
  bf16x8 kf0[4], kf1[4];
#pragma unroll
  for (int i = 0; i < 4; ++i) {
    const int tile = wv + i * 4;
    if (tile < ntiles) {
      const int s = tile * 16 + col;
      const int kw = min(wlo + (s & 31), 127);
      const unsigned short* kp =
          qkv + base + (size_t)((hlo + (s >> 5)) * 128 + kw) * 1536 + 512 + fg * 8;
      kf0[i] = *(const bf16x8*)kp;
      kf1[i] = *(const bf16x8*)(kp + 32);
    }
  }

  // ---- V pack (lane pairs r,r+1 via shfl) + swizzled dword writes ----
  {
    const bool wrt = (v & 1) == 0;
    const int pc = v >> 1;                    // p & 3
#pragma unroll
    for (int i = 0; i < 7; ++i) {
      int4 pv;
      pv.x = __shfl_xor(mv[i].x, 8);
      pv.y = __shfl_xor(mv[i].y, 8);
      pv.z = __shfl_xor(mv[i].z, 8);
      pv.w = __shfl_xor(mv[i].w, 8);
      if (wrt) {
        const int c = wv * 7 + i;             // chunk (pair>>2), 0..27
        const int cz = c ^ (u & 3);           // bits 0..1 only: cz <= 27
        const unsigned* md = (const unsigned*)&mv[i];
        const unsigned* pd = (const unsigned*)&pv;
#pragma unroll
        for (int j = 0; j < 8; ++j) {
          const unsigned own = md[j >> 1], par = pd[j >> 1];
          const unsigned dw = (j & 1) ? ((own >> 16) | (par & 0xffff0000u))
                                      : ((own & 0xffffu) | (par << 16));
          Vt2[(u * 8 + j) * VTS2 + cz * 4 + pc] = dw;
        }
      }
    }
  }

  // ---- QK^T: wave handles tiles wv, wv+4, wv+8, wv+12 (if < ntiles) ----
  f32x4 acc[4];
#pragma unroll
  for (int i = 0; i < 4; ++i) acc[i] = (f32x4){0.f, 0.f, 0.f, 0.f};
#pragma unroll
  for (int i = 0; i < 4; ++i) {
    const int tile = wv + i * 4;
    if (tile < ntiles) {
      acc[i] = __builtin_amdgcn_mfma_f32_16x16x32_bf16(qf[0], kf0[i], acc[i], 0, 0, 0);
      acc[i] = __builtin_amdgcn_mfma_f32_16x16x32_bf16(qf[1], kf1[i], acc[i], 0, 0, 0);
    }
  }

  // ---- scale + w-distance mask (S layout: col=key, row=fg*4+r=q) ----
#pragma unroll
  for (int i = 0; i < 4; ++i) {
    const int tile = wv + i * 4;
    if (tile < ntiles) {
      const int kw = wlo + (tile & 1) * 16 + col;   // nominal (unclamped)
#pragma unroll
      for (int r = 0; r < 4; ++r) {
        const int dw = kw - (w0 + fg * 4 + r);
        const bool valid = (dw >= -5) && (dw <= 5) && (kw <= 127);
        acc[i][r] = valid ? acc[i][r] * 0.125f : -__builtin_inff();
      }
    }
  }

  // ---- row max: own tiles -> 16-lane shuffle -> LDS cross-wave ----
  float gm[4], gs[4];
#pragma unroll
  for (int r = 0; r < 4; ++r) {
    float m = acc[0][r];
#pragma unroll
    for (int i = 1; i < 4; ++i)
      if (wv + i * 4 < ntiles) m = fmaxf(m, acc[i][r]);
#pragma unroll
    for (int off = 1; off <= 8; off <<= 1) m = fmaxf(m, __shfl_xor(m, off));
    if (col == 0) red[0][wv][fg * 4 + r] = m;
  }
  __syncthreads();
#pragma unroll
  for (int r = 0; r < 4; ++r) {
    const int row = fg * 4 + r;
    gm[r] = fmaxf(fmaxf(red[0][0][row], red[0][1][row]),
                  fmaxf(red[0][2][row], red[0][3][row]));
  }

  // ---- p = exp(s - max), row sums, write P (bf16, swizzled) ----
  float s4[4] = {0.f, 0.f, 0.f, 0.f};
#pragma unroll
  for (int i = 0; i < 4; ++i) {
    const int tile = wv + i * 4;
    if (tile < ntiles) {
#pragma unroll
      for (int r = 0; r < 4; ++r) {
        const float p = __expf(acc[i][r] - gm[r]);   // -inf -> 0
        s4[r] += p;
        const int row = fg * 4 + r;
        Pl[row * PLS + ((tile * 16 + col) ^ ((row & 7) << 3))] = f2bf(p);
      }
    }
  }
#pragma unroll
  for (int r = 0; r < 4; ++r) {
    float ss = s4[r];
#pragma unroll
    for (int off = 1; off <= 8; off <<= 1) ss += __shfl_xor(ss, off);
    if (col == 0) red[1][wv][fg * 4 + r] = ss;
  }
  __syncthreads();   // covers Pl + Vt2 writes + red[1]
#pragma unroll
  for (int r = 0; r < 4; ++r) {
    const int row = fg * 4 + r;
    gs[r] = (red[1][0][row] + red[1][1][row]) + (red[1][2][row] + red[1][3][row]);
  }

  // ---- PV: O[16q x 16d per wave]; A = Pl rows, B = Vt2 rows (d-major) ----
  f32x4 o = (f32x4){0.f, 0.f, 0.f, 0.f};
  const int dcol = wv * 16 + col;                       // this wave's d
  const int gz = (dcol >> 3) & 3;                       // matches write swizzle
  const int pz = (col & 7) << 3;                        // A row = col (=q)
  for (int ks = 0; ks < nh; ++ks) {
    bf16x8 pa = *(const bf16x8*)&Pl[col * PLS + ((ks * 32 + fg * 8) ^ pz)];
    bf16x8 vf = *(const bf16x8*)&Vt2[dcol * VTS2 + (((ks * 4 + fg) ^ gz) << 2)];
    o = __builtin_amdgcn_mfma_f32_16x16x32_bf16(pa, vf, o, 0, 0, 0);
  }

  // ---- normalize + store ----
#pragma unroll
  for (int r = 0; r < 4; ++r) {
    const int row = fg * 4 + r;
    const float val = o[r] / gs[r];
    att[((size_t)b * 2048 + h * 128 + w0 + row) * 512 + head * 64 + dcol] = f2bf(val);
  }
}

// ---------------------------------------------------------------------------
extern "C" void kernel_launch(void* const* d_in, const int* in_sizes, int n_in,
                              void* d_out, int out_size, void* d_ws, size_t ws_size,
                              hipStream_t stream) {
  const float* x      = (const float*)d_in[0];  // [4,2048,512]
  const float* w_qkv  = (const float*)d_in[1];  // [512,1536]
  const float* b_qkv  = (const float*)d_in[2];  // [1536]
  const float* w_proj = (const float*)d_in[3];  // [512,512]
  const float* b_proj = (const float*)d_in[4];  // [512]
  float* out = (float*)d_out;                   // [4,2048,512]

  char* ws = (char*)d_ws;
  unsigned short* xb     = (unsigned short*)(ws);             //  8,388,608 B (dead after GEMM1)
  unsigned short* att    = (unsigned short*)(ws);             //  aliases xb
  unsigned short* wqkvt  = (unsigned short*)(ws + 8388608);   //  1,572,864 B
  unsigned short* wprojt = (unsigned short*)(ws + 9961472);   //    524,288 B
  unsigned short* qkv    = (unsigned short*)(ws + 10485760);  // 25,165,824 B
  // total ws demand: 35,651,584 B

  // x -> bf16
  cvt_f32_to_bf16_kernel<<<4096, 256, 0, stream>>>(x, xb, 1048576);
  // w_qkv [512][1536] -> wqkvt [1536][512] bf16
  transpose_cvt_kernel<<<dim3(48, 16), dim3(32, 8), 0, stream>>>(w_qkv, wqkvt, 512, 1536);
  // w_proj [512][512] -> wprojt [512][512] bf16
  transpose_cvt_kernel<<<dim3(16, 16), dim3(32, 8), 0, stream>>>(w_proj, wprojt, 512, 512);

  // qkv = x @ w_qkv + b_qkv   (bf16 out)
  gemm_bt_kernel<true><<<dim3(64, 12), 256, 0, stream>>>(xb, wqkvt, b_qkv, qkv, 8192, 1536, 512);

  // local-window attention -> att (bf16, overwrites xb region)
  attn_local_kernel<<<dim3(8, 16, 32), 256, 0, stream>>>(qkv, att);

  // out = att @ w_proj + b_proj   (f32 out)
  gemm_bt_kernel<false><<<dim3(64, 4), 256, 0, stream>>>(att, wprojt, b_proj, out, 8192, 512, 512);
}